// Round 6
// baseline (739.133 us; speedup 1.0000x reference)
//
#include <hip/hip_runtime.h>
#include <hip/hip_cooperative_groups.h>
#include <math.h>

namespace cg = cooperative_groups;

#define V 128
#define M 256
#define CAT 64
#define B 256
#define LAYERS 4
#define K 4
#define AR 2
#define NNODES 32768
#define E (NNODES * K)
#define NUM_INPUT (V * M)
#define BASE (1 + NUM_INPUT)
#define TOTAL_ROWS (BASE + LAYERS * NNODES)   // 163841
#define NG (NNODES / 8)        // 4096 groups of 8 nodes per layer
#define L3N 32                 // fallback: nodes/block in fused layer-3 kernel
#define NPART_FB (NNODES / L3N)
#define R1BLK 32

typedef _Float16 half8 __attribute__((ext_vector_type(8)));
typedef _Float16 half4 __attribute__((ext_vector_type(4)));
typedef float float8_t __attribute__((ext_vector_type(8)));

// Per-layer storage offsets: stored = true_value + OFF (keeps fp16 small).
#define OFF_IN 5.2f
__device__ __forceinline__ float layer_off(int l) {
    return (l == 0) ? 11.4f : (l == 1) ? 23.5f : (l == 2) ? 47.5f : 95.5f;
}
__device__ __forceinline__ float row_off(int row) {
    if (row < BASE) return OFF_IN;
    return layer_off((row - BASE) >> 15);
}

union SMem {
    int cats[B];
    float vmat[B][9];     // [col][node-in-block], stride 9 (conflict-free)
    float red[B];
};

// ======================= Cooperative mega-kernel =========================
template <int GRID_>
__global__ __launch_bounds__(256, 2) void mega_kernel(
    const int* __restrict__ inputs,          // [B, V]
    const float* __restrict__ input_logits,  // [NUM_INPUT, CAT]
    const float* __restrict__ sum_logits,    // [LAYERS, N, K]
    const float* __restrict__ root_logits,   // [N]
    const int* __restrict__ child,           // [LAYERS, E, AR]
    float* __restrict__ out,                 // [B]
    _Float16* __restrict__ buf,              // [TOTAL_ROWS, B] fp16 (+offsets)
    float* __restrict__ pm, float* __restrict__ ps,     // [GRID_, B]
    float* __restrict__ pm2, float* __restrict__ ps2,   // [32, B]
    float* __restrict__ logZr)               // [1]
{
    constexpr int ITERS = NG / GRID_;              // gather groups per block
    constexpr int NB_IN = NUM_INPUT / GRID_;       // input nodes per block
    cg::grid_group grid = cg::this_grid();
    const int t = threadIdx.x;
    const int bid = blockIdx.x;

    __shared__ SMem sm;

    // ================= Phase A: input layer =================
    {
        const int vid = (bid * NB_IN) >> 8;        // constant within block
        sm.cats[t] = inputs[t * V + vid];
        __syncthreads();
        const int l = t & 63;
        const int w = t >> 6;
        const int c0 = sm.cats[4 * l + 0];
        const int c1 = sm.cats[4 * l + 1];
        const int c2 = sm.cats[4 * l + 2];
        const int c3 = sm.cats[4 * l + 3];
        #pragma unroll
        for (int it = 0; it < NB_IN / 4; ++it) {
            const int n = bid * NB_IN + it * 4 + w;     // one node per wave
            const float x = input_logits[n * CAT + l];
            float m = x;
            #pragma unroll
            for (int off = 32; off >= 1; off >>= 1) m = fmaxf(m, __shfl_xor(m, off));
            float s = __expf(x - m);
            #pragma unroll
            for (int off = 32; off >= 1; off >>= 1) s += __shfl_xor(s, off);
            const float logZ = m + __logf(s);
            half4 r;
            r[0] = (_Float16)(__shfl(x, c0) - logZ + OFF_IN);
            r[1] = (_Float16)(__shfl(x, c1) - logZ + OFF_IN);
            r[2] = (_Float16)(__shfl(x, c2) - logZ + OFF_IN);
            r[3] = (_Float16)(__shfl(x, c3) - logZ + OFF_IN);
            ((half4*)buf)[(1 + n) * (B / 4) + l] = r;
        }
        if (bid == 0 && t < B / 4) {                 // dummy row 0
            half4 z;
            z[0] = z[1] = z[2] = z[3] = (_Float16)OFF_IN;
            ((half4*)buf)[t] = z;
        }
    }
    __threadfence();
    grid.sync();

    // ================= Phases L0..L2: gather layers =================
    const int g = t >> 5;        // node within 8-node group
    const int lane = t & 31;     // half8 column index
    for (int l = 0; l < 3; ++l) {
        const int* ch_l = child + (size_t)l * E * AR;
        const float* sl_l = sum_logits + (size_t)l * NNODES * K;
        const float loff = layer_off(l);
        const int out_row0 = BASE + l * NNODES;
        const half8* bufv = (const half8*)buf;
        for (int it = 0; it < ITERS; ++it) {
            const int i = (bid + it * GRID_) * 8 + g;          // node id
            const int4 cA = ((const int4*)ch_l)[i * 2];
            const int4 cB = ((const int4*)ch_l)[i * 2 + 1];
            const float4 sl = ((const float4*)sl_l)[i];
            const float mm0 = fmaxf(fmaxf(sl.x, sl.y), fmaxf(sl.z, sl.w));
            const float lz = mm0 + __logf(__expf(sl.x - mm0) + __expf(sl.y - mm0) +
                                          __expf(sl.z - mm0) + __expf(sl.w - mm0));
            const float w0 = sl.x - lz - row_off(cA.x) - row_off(cA.y) + loff;
            const float w1 = sl.y - lz - row_off(cA.z) - row_off(cA.w) + loff;
            const float w2 = sl.z - lz - row_off(cB.x) - row_off(cB.y) + loff;
            const float w3 = sl.w - lz - row_off(cB.z) - row_off(cB.w) + loff;

            const half8 a0 = bufv[cA.x * (B / 8) + lane];
            const half8 b0 = bufv[cA.y * (B / 8) + lane];
            const half8 a1 = bufv[cA.z * (B / 8) + lane];
            const half8 b1 = bufv[cA.w * (B / 8) + lane];
            const half8 a2 = bufv[cB.x * (B / 8) + lane];
            const half8 b2 = bufv[cB.y * (B / 8) + lane];
            const half8 a3 = bufv[cB.z * (B / 8) + lane];
            const half8 b3 = bufv[cB.w * (B / 8) + lane];

            const float8_t v0 = __builtin_convertvector(a0, float8_t) +
                                __builtin_convertvector(b0, float8_t) + w0;
            const float8_t v1 = __builtin_convertvector(a1, float8_t) +
                                __builtin_convertvector(b1, float8_t) + w1;
            const float8_t v2 = __builtin_convertvector(a2, float8_t) +
                                __builtin_convertvector(b2, float8_t) + w2;
            const float8_t v3 = __builtin_convertvector(a3, float8_t) +
                                __builtin_convertvector(b3, float8_t) + w3;

            half8 r;
            #pragma unroll
            for (int j = 0; j < 8; ++j) {
                const float mm = fmaxf(fmaxf(v0[j], v1[j]), fmaxf(v2[j], v3[j]));
                const float ss = __expf(v0[j] - mm) + __expf(v1[j] - mm) +
                                 __expf(v2[j] - mm) + __expf(v3[j] - mm);
                r[j] = (_Float16)(mm + __logf(ss));
            }
            ((half8*)buf)[(out_row0 + i) * (B / 8) + lane] = r;
        }
        __threadfence();
        grid.sync();
    }

    // ============= Phase L3: fused layer 3 + root partial =============
    {
        const int* ch_l = child + (size_t)3 * E * AR;
        const float* sl_l = sum_logits + (size_t)3 * NNODES * K;
        const float loff = layer_off(3);
        const half8* bufv = (const half8*)buf;
        float mB = -INFINITY, sB = 0.0f;
        for (int it = 0; it < ITERS; ++it) {
            const int i = (bid + it * GRID_) * 8 + g;
            const int4 cA = ((const int4*)ch_l)[i * 2];
            const int4 cB = ((const int4*)ch_l)[i * 2 + 1];
            const float4 sl = ((const float4*)sl_l)[i];
            const float mm0 = fmaxf(fmaxf(sl.x, sl.y), fmaxf(sl.z, sl.w));
            const float lz = mm0 + __logf(__expf(sl.x - mm0) + __expf(sl.y - mm0) +
                                          __expf(sl.z - mm0) + __expf(sl.w - mm0));
            const float w0 = sl.x - lz - row_off(cA.x) - row_off(cA.y) + loff;
            const float w1 = sl.y - lz - row_off(cA.z) - row_off(cA.w) + loff;
            const float w2 = sl.z - lz - row_off(cB.x) - row_off(cB.y) + loff;
            const float w3 = sl.w - lz - row_off(cB.z) - row_off(cB.w) + loff;

            const half8 a0 = bufv[cA.x * (B / 8) + lane];
            const half8 b0 = bufv[cA.y * (B / 8) + lane];
            const half8 a1 = bufv[cA.z * (B / 8) + lane];
            const half8 b1 = bufv[cA.w * (B / 8) + lane];
            const half8 a2 = bufv[cB.x * (B / 8) + lane];
            const half8 b2 = bufv[cB.y * (B / 8) + lane];
            const half8 a3 = bufv[cB.z * (B / 8) + lane];
            const half8 b3 = bufv[cB.w * (B / 8) + lane];

            const float8_t v0 = __builtin_convertvector(a0, float8_t) +
                                __builtin_convertvector(b0, float8_t) + w0;
            const float8_t v1 = __builtin_convertvector(a1, float8_t) +
                                __builtin_convertvector(b1, float8_t) + w1;
            const float8_t v2 = __builtin_convertvector(a2, float8_t) +
                                __builtin_convertvector(b2, float8_t) + w2;
            const float8_t v3 = __builtin_convertvector(a3, float8_t) +
                                __builtin_convertvector(b3, float8_t) + w3;

            const float radd = root_logits[i] - loff;
            float rr[8];
            #pragma unroll
            for (int j = 0; j < 8; ++j) {
                const float mm = fmaxf(fmaxf(v0[j], v1[j]), fmaxf(v2[j], v3[j]));
                const float ss = __expf(v0[j] - mm) + __expf(v1[j] - mm) +
                                 __expf(v2[j] - mm) + __expf(v3[j] - mm);
                rr[j] = mm + __logf(ss) + radd;
            }
            __syncthreads();
            #pragma unroll
            for (int j = 0; j < 8; ++j) sm.vmat[8 * lane + j][g] = rr[j];
            __syncthreads();
            float m8 = sm.vmat[t][0];
            #pragma unroll
            for (int q = 1; q < 8; ++q) m8 = fmaxf(m8, sm.vmat[t][q]);
            float s8 = 0.0f;
            #pragma unroll
            for (int q = 0; q < 8; ++q) s8 += __expf(sm.vmat[t][q] - m8);
            const float nm = fmaxf(mB, m8);
            sB = sB * __expf(mB - nm) + s8 * __expf(m8 - nm);
            mB = nm;
        }
        pm[bid * B + t] = mB;
        ps[bid * B + t] = sB;
    }
    __threadfence();
    grid.sync();

    // ============= Phase R1: reduce GRID_ partials -> 32; logZ =============
    if (bid < 32) {
        constexpr int Q = GRID_ / 32;
        const int p0 = bid * Q;
        float m = -INFINITY;
        #pragma unroll 4
        for (int q = 0; q < Q; ++q) m = fmaxf(m, pm[(p0 + q) * B + t]);
        float s = 0.0f;
        #pragma unroll 4
        for (int q = 0; q < Q; ++q)
            s += ps[(p0 + q) * B + t] * __expf(pm[(p0 + q) * B + t] - m);
        pm2[bid * B + t] = m;
        ps2[bid * B + t] = s;
    } else if (bid == 32) {
        float a0 = -INFINITY, a1 = -INFINITY, a2 = -INFINITY, a3 = -INFINITY;
        #pragma unroll 4
        for (int n = t; n < NNODES; n += 1024) {
            a0 = fmaxf(a0, root_logits[n]);
            a1 = fmaxf(a1, root_logits[n + 256]);
            a2 = fmaxf(a2, root_logits[n + 512]);
            a3 = fmaxf(a3, root_logits[n + 768]);
        }
        sm.red[t] = fmaxf(fmaxf(a0, a1), fmaxf(a2, a3));
        __syncthreads();
        for (int off = 128; off >= 1; off >>= 1) {
            if (t < off) sm.red[t] = fmaxf(sm.red[t], sm.red[t + off]);
            __syncthreads();
        }
        const float gm = sm.red[0];
        __syncthreads();
        float b0 = 0.f, b1 = 0.f, b2 = 0.f, b3 = 0.f;
        #pragma unroll 4
        for (int n = t; n < NNODES; n += 1024) {
            b0 += __expf(root_logits[n]       - gm);
            b1 += __expf(root_logits[n + 256] - gm);
            b2 += __expf(root_logits[n + 512] - gm);
            b3 += __expf(root_logits[n + 768] - gm);
        }
        sm.red[t] = (b0 + b1) + (b2 + b3);
        __syncthreads();
        for (int off = 128; off >= 1; off >>= 1) {
            if (t < off) sm.red[t] += sm.red[t + off];
            __syncthreads();
        }
        if (t == 0) logZr[0] = gm + __logf(sm.red[0]);
    }
    __threadfence();
    grid.sync();

    // ================= Phase R2: final combine =================
    if (bid == 0) {
        float m = -INFINITY;
        #pragma unroll
        for (int p = 0; p < 32; ++p) m = fmaxf(m, pm2[p * B + t]);
        float s = 0.0f;
        #pragma unroll
        for (int p = 0; p < 32; ++p)
            s += ps2[p * B + t] * __expf(pm2[p * B + t] - m);
        out[t] = m + __logf(s) - logZr[0];
    }
}

// ======================= Fallback path (round-4, proven) ==================
__global__ __launch_bounds__(256) void input_layer_kernel(
    const int* __restrict__ inputs, const float* __restrict__ input_logits,
    _Float16* __restrict__ buf)
{
    __shared__ float lg[4][CAT];
    __shared__ int cats[B];
    __shared__ float lzs[4];
    const int t = threadIdx.x;
    const int n0 = blockIdx.x * 4;

    lg[t >> 6][t & 63] = input_logits[(size_t)n0 * CAT + t];
    cats[t] = inputs[t * V + (n0 >> 8)];
    __syncthreads();

    const int w = t >> 6;
    const int l = t & 63;
    float x = lg[w][l];
    float m = x;
    #pragma unroll
    for (int off = 32; off >= 1; off >>= 1) m = fmaxf(m, __shfl_xor(m, off));
    float s = __expf(x - m);
    #pragma unroll
    for (int off = 32; off >= 1; off >>= 1) s += __shfl_xor(s, off);
    if (l == 0) lzs[w] = m + __logf(s);
    __syncthreads();

    const float logZ = lzs[w];
    half4 r;
    #pragma unroll
    for (int j = 0; j < 4; ++j) {
        const int c = cats[4 * l + j];
        r[j] = (_Float16)(lg[w][c] - logZ + OFF_IN);
    }
    ((half4*)buf)[(size_t)(1 + n0 + w) * (B / 4) + l] = r;

    if (blockIdx.x == 0 && t < B / 4) {
        half4 z;
        z[0] = z[1] = z[2] = z[3] = (_Float16)OFF_IN;
        ((half4*)buf)[t] = z;
    }
}

__global__ __launch_bounds__(256) void layer_kernel(
    const int* __restrict__ child, const float* __restrict__ slog,
    _Float16* __restrict__ buf, int out_row0, int layer)
{
    __shared__ int ch[8][K * AR];
    __shared__ float w[8][K];
    const int t = threadIdx.x;
    const int i0 = blockIdx.x * 8;

    if (t < 64) ((int*)ch)[t] = child[(size_t)i0 * (K * AR) + t];
    __syncthreads();

    if (t < 32) {
        const float x = slog[(size_t)i0 * K + t];
        float mm = fmaxf(x, __shfl_xor(x, 1));
        mm = fmaxf(mm, __shfl_xor(mm, 2));
        float e = __expf(x - mm);
        float ss = e + __shfl_xor(e, 1);
        ss += __shfl_xor(ss, 2);
        const float lz = mm + __logf(ss);
        const int j = t >> 2, k = t & 3;
        w[j][k] = x - lz - row_off(ch[j][2 * k]) - row_off(ch[j][2 * k + 1])
                  + layer_off(layer);
    }
    __syncthreads();

    const int g = t >> 5;
    const int l = t & 31;
    const half8* bufv = (const half8*)buf;

    float8_t v[K];
    #pragma unroll
    for (int k = 0; k < K; ++k) {
        const half8 a = bufv[ch[g][2 * k]     * (B / 8) + l];
        const half8 b = bufv[ch[g][2 * k + 1] * (B / 8) + l];
        v[k] = __builtin_convertvector(a, float8_t) +
               __builtin_convertvector(b, float8_t) + w[g][k];
    }

    half8 r;
    #pragma unroll
    for (int j = 0; j < 8; ++j) {
        const float mm = fmaxf(fmaxf(v[0][j], v[1][j]), fmaxf(v[2][j], v[3][j]));
        const float ss = __expf(v[0][j] - mm) + __expf(v[1][j] - mm) +
                         __expf(v[2][j] - mm) + __expf(v[3][j] - mm);
        r[j] = (_Float16)(mm + __logf(ss));
    }
    ((half8*)buf)[(out_row0 + i0 + g) * (B / 8) + l] = r;
}

__global__ __launch_bounds__(1024) void layer3_root_kernel(
    const int* __restrict__ child, const float* __restrict__ slog,
    const _Float16* __restrict__ buf, const float* __restrict__ rlog,
    float* __restrict__ pm, float* __restrict__ ps)
{
    __shared__ int ch[L3N][K * AR];
    __shared__ float w[L3N][K];
    __shared__ float rl[L3N];
    __shared__ float vmat[B][L3N + 1];
    const int t = threadIdx.x;
    const int i0 = blockIdx.x * L3N;
    const float off3 = layer_off(3);

    if (t < L3N * 8) ((int*)ch)[t] = child[(size_t)i0 * (K * AR) + t];
    if (t >= 512 && t < 512 + L3N) rl[t - 512] = rlog[i0 + (t - 512)];
    __syncthreads();

    if (t < L3N * 4) {
        const float x = slog[(size_t)i0 * K + t];
        float mm = fmaxf(x, __shfl_xor(x, 1));
        mm = fmaxf(mm, __shfl_xor(mm, 2));
        float e = __expf(x - mm);
        float ss = e + __shfl_xor(e, 1);
        ss += __shfl_xor(ss, 2);
        const float lz = mm + __logf(ss);
        const int j = t >> 2, k = t & 3;
        w[j][k] = x - lz - row_off(ch[j][2 * k]) - row_off(ch[j][2 * k + 1])
                  + off3;
    }
    __syncthreads();

    const int g = t >> 5;
    const int l = t & 31;

    const half8* bufv = (const half8*)buf;
    float8_t v[K];
    #pragma unroll
    for (int k = 0; k < K; ++k) {
        const half8 a = bufv[ch[g][2 * k]     * (B / 8) + l];
        const half8 b = bufv[ch[g][2 * k + 1] * (B / 8) + l];
        v[k] = __builtin_convertvector(a, float8_t) +
               __builtin_convertvector(b, float8_t) + w[g][k];
    }

    const float radd = rl[g] - off3;
    #pragma unroll
    for (int j = 0; j < 8; ++j) {
        const float mm = fmaxf(fmaxf(v[0][j], v[1][j]), fmaxf(v[2][j], v[3][j]));
        const float ss = __expf(v[0][j] - mm) + __expf(v[1][j] - mm) +
                         __expf(v[2][j] - mm) + __expf(v[3][j] - mm);
        vmat[8 * l + j][g] = mm + __logf(ss) + radd;
    }
    __syncthreads();

    if (t < B) {
        float m = -INFINITY;
        #pragma unroll
        for (int q = 0; q < L3N; ++q) m = fmaxf(m, vmat[t][q]);
        float s = 0.0f;
        #pragma unroll
        for (int q = 0; q < L3N; ++q) s += __expf(vmat[t][q] - m);
        pm[blockIdx.x * B + t] = m;
        ps[blockIdx.x * B + t] = s;
    }
}

__global__ __launch_bounds__(256) void root_reduce1(
    const float* __restrict__ pm, const float* __restrict__ ps,
    float* __restrict__ pm2, float* __restrict__ ps2)
{
    const int j = blockIdx.x;
    const int c = threadIdx.x;
    const int Q = NPART_FB / R1BLK;
    const int p0 = j * Q;

    float m = -INFINITY;
    #pragma unroll 8
    for (int q = 0; q < Q; ++q) m = fmaxf(m, pm[(p0 + q) * B + c]);
    float s = 0.0f;
    #pragma unroll 8
    for (int q = 0; q < Q; ++q)
        s += ps[(p0 + q) * B + c] * __expf(pm[(p0 + q) * B + c] - m);
    pm2[j * B + c] = m;
    ps2[j * B + c] = s;
}

__global__ __launch_bounds__(256) void root_combine_kernel(
    const float* __restrict__ rlog,
    const float* __restrict__ pm2, const float* __restrict__ ps2,
    float* __restrict__ out)
{
    __shared__ float red[256];
    const int t = threadIdx.x;

    float a0 = -INFINITY, a1 = -INFINITY, a2 = -INFINITY, a3 = -INFINITY;
    #pragma unroll 4
    for (int n = t; n < NNODES; n += 1024) {
        a0 = fmaxf(a0, rlog[n]);
        a1 = fmaxf(a1, rlog[n + 256]);
        a2 = fmaxf(a2, rlog[n + 512]);
        a3 = fmaxf(a3, rlog[n + 768]);
    }
    red[t] = fmaxf(fmaxf(a0, a1), fmaxf(a2, a3));
    __syncthreads();
    for (int off = 128; off >= 1; off >>= 1) {
        if (t < off) red[t] = fmaxf(red[t], red[t + off]);
        __syncthreads();
    }
    const float gm = red[0];
    __syncthreads();

    float b0 = 0.f, b1 = 0.f, b2 = 0.f, b3 = 0.f;
    #pragma unroll 4
    for (int n = t; n < NNODES; n += 1024) {
        b0 += __expf(rlog[n]       - gm);
        b1 += __expf(rlog[n + 256] - gm);
        b2 += __expf(rlog[n + 512] - gm);
        b3 += __expf(rlog[n + 768] - gm);
    }
    red[t] = (b0 + b1) + (b2 + b3);
    __syncthreads();
    for (int off = 128; off >= 1; off >>= 1) {
        if (t < off) red[t] += red[t + off];
        __syncthreads();
    }
    const float logZ = gm + __logf(red[0]);

    float m = -INFINITY;
    #pragma unroll 8
    for (int p = 0; p < R1BLK; ++p) m = fmaxf(m, pm2[p * B + t]);
    float s = 0.0f;
    #pragma unroll 8
    for (int p = 0; p < R1BLK; ++p)
        s += ps2[p * B + t] * __expf(pm2[p * B + t] - m);
    out[t] = m + __logf(s) - logZ;
}

// ========================== Launcher ==========================
extern "C" void kernel_launch(void* const* d_in, const int* in_sizes, int n_in,
                              void* d_out, int out_size, void* d_ws, size_t ws_size,
                              hipStream_t stream) {
    const int*   inputs       = (const int*)d_in[0];    // [B, V]
    const float* input_logits = (const float*)d_in[1];  // [NUM_INPUT, CAT]
    const float* sum_logits   = (const float*)d_in[2];  // [LAYERS, N, K]
    const float* root_logits  = (const float*)d_in[3];  // [N]
    const int*   child        = (const int*)d_in[4];    // [LAYERS, E, AR]
    float* out = (float*)d_out;                          // [B, 1]

    _Float16* buf = (_Float16*)d_ws;                     // [TOTAL_ROWS, B] fp16
    float* pm    = (float*)(buf + (size_t)TOTAL_ROWS * B);   // [1024, B]
    float* ps    = pm  + (size_t)1024 * B;                   // [1024, B]
    float* pm2   = ps  + (size_t)1024 * B;                   // [32, B]
    float* ps2   = pm2 + (size_t)32 * B;                     // [32, B]
    float* logZr = ps2 + (size_t)32 * B;                     // [1]

    // --- decide coop feasibility with host-side (capture-safe) queries ---
    int dev = 0;
    (void)hipGetDevice(&dev);
    int coop_ok = 0;
    (void)hipDeviceGetAttribute(&coop_ok, hipDeviceAttributeCooperativeLaunch, dev);
    int num_cu = 0;
    (void)hipDeviceGetAttribute(&num_cu, hipDeviceAttributeMultiprocessorCount, dev);

    int grid_pick = 0;  // 0 = fallback, else coop grid size
    if (coop_ok && num_cu > 0) {
        int mb1024 = 0, mb512 = 0;
        (void)hipOccupancyMaxActiveBlocksPerMultiprocessor(&mb1024, mega_kernel<1024>, 256, 0);
        (void)hipOccupancyMaxActiveBlocksPerMultiprocessor(&mb512,  mega_kernel<512>,  256, 0);
        if ((long)mb1024 * num_cu >= 1024) grid_pick = 1024;
        else if ((long)mb512 * num_cu >= 512) grid_pick = 512;
    }

    hipError_t lerr = hipErrorUnknown;
    if (grid_pick) {
        void* kargs[] = {
            (void*)&inputs, (void*)&input_logits, (void*)&sum_logits,
            (void*)&root_logits, (void*)&child, (void*)&out,
            (void*)&buf, (void*)&pm, (void*)&ps, (void*)&pm2, (void*)&ps2,
            (void*)&logZr
        };
        const void* fn = (grid_pick == 1024) ? (const void*)mega_kernel<1024>
                                             : (const void*)mega_kernel<512>;
        lerr = hipLaunchCooperativeKernel(fn, dim3(grid_pick), dim3(256),
                                          kargs, 0, stream);
    }

    if (lerr != hipSuccess) {
        // -------- proven multi-kernel path --------
        input_layer_kernel<<<NUM_INPUT / 4, 256, 0, stream>>>(inputs, input_logits, buf);
        for (int l = 0; l < LAYERS - 1; ++l) {
            layer_kernel<<<NNODES / 8, 256, 0, stream>>>(
                child + (size_t)l * E * AR,
                sum_logits + (size_t)l * NNODES * K,
                buf, BASE + l * NNODES, l);
        }
        layer3_root_kernel<<<NPART_FB, 1024, 0, stream>>>(
            child + (size_t)(LAYERS - 1) * E * AR,
            sum_logits + (size_t)(LAYERS - 1) * NNODES * K,
            buf, root_logits, pm, ps);
        root_reduce1<<<R1BLK, 256, 0, stream>>>(pm, ps, pm2, ps2);
        root_combine_kernel<<<1, 256, 0, stream>>>(root_logits, pm2, ps2, out);
    }
}

// Round 7
// 131.436 us; speedup vs baseline: 5.6235x; 5.6235x over previous
//
#include <hip/hip_runtime.h>
#include <math.h>

#define V 128
#define M 256
#define CAT 64
#define B 256
#define LAYERS 4
#define K 4
#define AR 2
#define NNODES 32768
#define E (NNODES * K)
#define NUM_INPUT (V * M)
#define BASE (1 + NUM_INPUT)
#define TOTAL_ROWS (BASE + LAYERS * NNODES)   // 163841
#define L3BLKS 256            // layer3_root grid
#define L3ITER 4              // 128 nodes/block, 32 per iteration
#define NPART 256             // partials after layer3_root

typedef _Float16 half8 __attribute__((ext_vector_type(8)));
typedef _Float16 half4 __attribute__((ext_vector_type(4)));
typedef float float8_t __attribute__((ext_vector_type(8)));

// Per-layer storage offsets: stored = true_value + OFF (keeps fp16 small).
#define OFF_IN 5.2f
__device__ __forceinline__ float layer_off(int l) {
    return (l == 0) ? 11.4f : (l == 1) ? 23.5f : (l == 2) ? 47.5f : 95.5f;
}
__device__ __forceinline__ float row_off(int row) {
    if (row < BASE) return OFF_IN;
    return layer_off((row - BASE) >> 15);
}

// ============ Kernel A: input layer (16 nodes/block, shuffle gather) ========
__global__ __launch_bounds__(256) void input_layer_kernel(
    const int* __restrict__ inputs,          // [B, V]
    const float* __restrict__ input_logits,  // [NUM_INPUT, CAT]
    _Float16* __restrict__ buf)              // [TOTAL_ROWS, B]
{
    __shared__ int cats[B];
    const int t = threadIdx.x;
    const int n0 = blockIdx.x * 16;
    const int vid = n0 >> 8;                 // constant within block

    cats[t] = inputs[t * V + vid];
    __syncthreads();

    const int l = t & 63;
    const int w = t >> 6;
    const int c0 = cats[4 * l + 0];
    const int c1 = cats[4 * l + 1];
    const int c2 = cats[4 * l + 2];
    const int c3 = cats[4 * l + 3];

    #pragma unroll
    for (int it = 0; it < 4; ++it) {
        const int n = n0 + it * 4 + w;       // one node per wave
        const float x = input_logits[n * CAT + l];
        float m = x;
        #pragma unroll
        for (int off = 32; off >= 1; off >>= 1) m = fmaxf(m, __shfl_xor(m, off));
        float s = __expf(x - m);
        #pragma unroll
        for (int off = 32; off >= 1; off >>= 1) s += __shfl_xor(s, off);
        const float logZ = m + __logf(s);
        half4 r;
        r[0] = (_Float16)(__shfl(x, c0) - logZ + OFF_IN);
        r[1] = (_Float16)(__shfl(x, c1) - logZ + OFF_IN);
        r[2] = (_Float16)(__shfl(x, c2) - logZ + OFF_IN);
        r[3] = (_Float16)(__shfl(x, c3) - logZ + OFF_IN);
        ((half4*)buf)[(1 + n) * (B / 4) + l] = r;
    }

    if (blockIdx.x == 0 && t < B / 4) {      // dummy row 0
        half4 z;
        z[0] = z[1] = z[2] = z[3] = (_Float16)OFF_IN;
        ((half4*)buf)[t] = z;
    }
}

// ============ Kernel B: gather layer (16 nodes/block, 2x MLP) ==============
__global__ __launch_bounds__(256) void layer_kernel(
    const int* __restrict__ child,   // [E, AR] for this layer
    const float* __restrict__ slog,  // [N, K]
    _Float16* __restrict__ buf,
    int out_row0, int layer)
{
    __shared__ int ch[16][K * AR];
    __shared__ float w[16][K];
    const int t = threadIdx.x;
    const int i0 = blockIdx.x * 16;

    if (t < 128) ((int*)ch)[t] = child[(size_t)i0 * (K * AR) + t];
    __syncthreads();

    if (t < 64) {   // 16 nodes x 4 logits; 4-lane-group LSE
        const float x = slog[(size_t)i0 * K + t];
        float mm = fmaxf(x, __shfl_xor(x, 1));
        mm = fmaxf(mm, __shfl_xor(mm, 2));
        float e = __expf(x - mm);
        float ss = e + __shfl_xor(e, 1);
        ss += __shfl_xor(ss, 2);
        const float lz = mm + __logf(ss);
        const int j = t >> 2, k = t & 3;
        w[j][k] = x - lz - row_off(ch[j][2 * k]) - row_off(ch[j][2 * k + 1])
                  + layer_off(layer);
    }
    __syncthreads();

    const int g = t >> 5;      // 0..7: node A = i0+g, node B = i0+8+g
    const int lane = t & 31;
    const half8* bufv = (const half8*)buf;

    // issue all 16 row loads before any use (2x memory-level parallelism)
    half8 ra[8], rb[8];
    #pragma unroll
    for (int c = 0; c < 8; ++c) ra[c] = bufv[ch[g][c]     * (B / 8) + lane];
    #pragma unroll
    for (int c = 0; c < 8; ++c) rb[c] = bufv[ch[8 + g][c] * (B / 8) + lane];

    float8_t va[K];
    #pragma unroll
    for (int k = 0; k < K; ++k)
        va[k] = __builtin_convertvector(ra[2 * k], float8_t) +
                __builtin_convertvector(ra[2 * k + 1], float8_t) + w[g][k];
    half8 rA;
    #pragma unroll
    for (int j = 0; j < 8; ++j) {
        const float mm = fmaxf(fmaxf(va[0][j], va[1][j]), fmaxf(va[2][j], va[3][j]));
        const float ss = __expf(va[0][j] - mm) + __expf(va[1][j] - mm) +
                         __expf(va[2][j] - mm) + __expf(va[3][j] - mm);
        rA[j] = (_Float16)(mm + __logf(ss));
    }
    ((half8*)buf)[(out_row0 + i0 + g) * (B / 8) + lane] = rA;

    float8_t vb[K];
    #pragma unroll
    for (int k = 0; k < K; ++k)
        vb[k] = __builtin_convertvector(rb[2 * k], float8_t) +
                __builtin_convertvector(rb[2 * k + 1], float8_t) + w[8 + g][k];
    half8 rB;
    #pragma unroll
    for (int j = 0; j < 8; ++j) {
        const float mm = fmaxf(fmaxf(vb[0][j], vb[1][j]), fmaxf(vb[2][j], vb[3][j]));
        const float ss = __expf(vb[0][j] - mm) + __expf(vb[1][j] - mm) +
                         __expf(vb[2][j] - mm) + __expf(vb[3][j] - mm);
        rB[j] = (_Float16)(mm + __logf(ss));
    }
    ((half8*)buf)[(out_row0 + i0 + 8 + g) * (B / 8) + lane] = rB;
}

// ============ Kernel B3: fused layer 3 + root partial (256 blocks) =========
// Block handles 128 nodes over 4 iterations; online-merges per-column LSE.
__global__ __launch_bounds__(1024) void layer3_root_kernel(
    const int* __restrict__ child,   // layer-3 [E, AR]
    const float* __restrict__ slog,  // layer-3 [N, K]
    const _Float16* __restrict__ buf,
    const float* __restrict__ rlog,  // [N]
    float* __restrict__ pm, float* __restrict__ ps)  // [NPART, B]
{
    __shared__ int ch[32][K * AR];
    __shared__ float w[32][K];
    __shared__ float rl[32];
    __shared__ float vmat[B][33];
    const int t = threadIdx.x;
    const float off3 = layer_off(3);
    const int g = t >> 5;      // node within 32-node group (0..31)
    const int lane = t & 31;

    float mB = -INFINITY, sB = 0.0f;

    for (int it = 0; it < L3ITER; ++it) {
        const int i0 = (blockIdx.x * L3ITER + it) * 32;
        __syncthreads();   // prev iter's ch/w/vmat reads complete
        if (t < 256) ((int*)ch)[t] = child[(size_t)i0 * (K * AR) + t];
        if (t >= 512 && t < 544) rl[t - 512] = rlog[i0 + (t - 512)];
        __syncthreads();
        if (t < 128) {
            const float x = slog[(size_t)i0 * K + t];
            float mm = fmaxf(x, __shfl_xor(x, 1));
            mm = fmaxf(mm, __shfl_xor(mm, 2));
            float e = __expf(x - mm);
            float ss = e + __shfl_xor(e, 1);
            ss += __shfl_xor(ss, 2);
            const float lz = mm + __logf(ss);
            const int j = t >> 2, k = t & 3;
            w[j][k] = x - lz - row_off(ch[j][2 * k]) - row_off(ch[j][2 * k + 1])
                      + off3;
        }
        __syncthreads();

        const half8* bufv = (const half8*)buf;
        float8_t v[K];
        #pragma unroll
        for (int k = 0; k < K; ++k) {
            const half8 a = bufv[ch[g][2 * k]     * (B / 8) + lane];
            const half8 b = bufv[ch[g][2 * k + 1] * (B / 8) + lane];
            v[k] = __builtin_convertvector(a, float8_t) +
                   __builtin_convertvector(b, float8_t) + w[g][k];
        }
        const float radd = rl[g] - off3;
        #pragma unroll
        for (int j = 0; j < 8; ++j) {
            const float mm = fmaxf(fmaxf(v[0][j], v[1][j]), fmaxf(v[2][j], v[3][j]));
            const float ss = __expf(v[0][j] - mm) + __expf(v[1][j] - mm) +
                             __expf(v[2][j] - mm) + __expf(v[3][j] - mm);
            vmat[8 * lane + j][g] = mm + __logf(ss) + radd;
        }
        __syncthreads();

        if (t < B) {    // per-column LSE over 32 nodes, online-merge
            float m8 = vmat[t][0];
            #pragma unroll
            for (int q = 1; q < 32; ++q) m8 = fmaxf(m8, vmat[t][q]);
            float s8 = 0.0f;
            #pragma unroll
            for (int q = 0; q < 32; ++q) s8 += __expf(vmat[t][q] - m8);
            const float nm = fmaxf(mB, m8);
            sB = sB * __expf(mB - nm) + s8 * __expf(m8 - nm);
            mB = nm;
        }
    }
    if (t < B) {
        pm[blockIdx.x * B + t] = mB;
        ps[blockIdx.x * B + t] = sB;
    }
}

// ============ Kernel D: final combine (256 partials) + root logZ ===========
__global__ __launch_bounds__(256) void root_final_kernel(
    const float* __restrict__ rlog,
    const float* __restrict__ pm, const float* __restrict__ ps,
    float* __restrict__ out)
{
    __shared__ float red[256];
    const int t = threadIdx.x;

    // logZ of root logits (two-pass, 4 accumulators)
    float a0 = -INFINITY, a1 = -INFINITY, a2 = -INFINITY, a3 = -INFINITY;
    #pragma unroll 4
    for (int n = t; n < NNODES; n += 1024) {
        a0 = fmaxf(a0, rlog[n]);
        a1 = fmaxf(a1, rlog[n + 256]);
        a2 = fmaxf(a2, rlog[n + 512]);
        a3 = fmaxf(a3, rlog[n + 768]);
    }
    red[t] = fmaxf(fmaxf(a0, a1), fmaxf(a2, a3));
    __syncthreads();
    for (int off = 128; off >= 1; off >>= 1) {
        if (t < off) red[t] = fmaxf(red[t], red[t + off]);
        __syncthreads();
    }
    const float gm = red[0];
    __syncthreads();

    float b0 = 0.f, b1 = 0.f, b2 = 0.f, b3 = 0.f;
    #pragma unroll 4
    for (int n = t; n < NNODES; n += 1024) {
        b0 += __expf(rlog[n]       - gm);
        b1 += __expf(rlog[n + 256] - gm);
        b2 += __expf(rlog[n + 512] - gm);
        b3 += __expf(rlog[n + 768] - gm);
    }
    red[t] = (b0 + b1) + (b2 + b3);
    __syncthreads();
    for (int off = 128; off >= 1; off >>= 1) {
        if (t < off) red[t] += red[t + off];
        __syncthreads();
    }
    const float logZ = gm + __logf(red[0]);

    // combine NPART partials for batch column t (coalesced across t)
    float m0 = -INFINITY, m1 = -INFINITY, m2 = -INFINITY, m3 = -INFINITY;
    #pragma unroll 8
    for (int p = 0; p < NPART; p += 4) {
        m0 = fmaxf(m0, pm[(p)     * B + t]);
        m1 = fmaxf(m1, pm[(p + 1) * B + t]);
        m2 = fmaxf(m2, pm[(p + 2) * B + t]);
        m3 = fmaxf(m3, pm[(p + 3) * B + t]);
    }
    const float m = fmaxf(fmaxf(m0, m1), fmaxf(m2, m3));

    float s0 = 0.f, s1 = 0.f, s2 = 0.f, s3 = 0.f;
    #pragma unroll 8
    for (int p = 0; p < NPART; p += 4) {
        s0 += ps[(p)     * B + t] * __expf(pm[(p)     * B + t] - m);
        s1 += ps[(p + 1) * B + t] * __expf(pm[(p + 1) * B + t] - m);
        s2 += ps[(p + 2) * B + t] * __expf(pm[(p + 2) * B + t] - m);
        s3 += ps[(p + 3) * B + t] * __expf(pm[(p + 3) * B + t] - m);
    }
    out[t] = m + __logf((s0 + s1) + (s2 + s3)) - logZ;
}

// ========================== Launcher ==========================
extern "C" void kernel_launch(void* const* d_in, const int* in_sizes, int n_in,
                              void* d_out, int out_size, void* d_ws, size_t ws_size,
                              hipStream_t stream) {
    const int*   inputs       = (const int*)d_in[0];    // [B, V]
    const float* input_logits = (const float*)d_in[1];  // [NUM_INPUT, CAT]
    const float* sum_logits   = (const float*)d_in[2];  // [LAYERS, N, K]
    const float* root_logits  = (const float*)d_in[3];  // [N]
    const int*   child        = (const int*)d_in[4];    // [LAYERS, E, AR]
    float* out = (float*)d_out;                          // [B, 1]

    _Float16* buf = (_Float16*)d_ws;                     // [TOTAL_ROWS, B] fp16
    float* pm = (float*)(buf + (size_t)TOTAL_ROWS * B);  // [NPART, B]
    float* ps = pm + (size_t)NPART * B;                  // [NPART, B]

    input_layer_kernel<<<NUM_INPUT / 16, 256, 0, stream>>>(inputs, input_logits, buf);

    for (int l = 0; l < LAYERS - 1; ++l) {
        layer_kernel<<<NNODES / 16, 256, 0, stream>>>(
            child + (size_t)l * E * AR,
            sum_logits + (size_t)l * NNODES * K,
            buf, BASE + l * NNODES, l);
    }

    layer3_root_kernel<<<L3BLKS, 1024, 0, stream>>>(
        child + (size_t)(LAYERS - 1) * E * AR,
        sum_logits + (size_t)(LAYERS - 1) * NNODES * K,
        buf, root_logits, pm, ps);

    root_final_kernel<<<1, 256, 0, stream>>>(root_logits, pm, ps, out);
}